// Round 9
// baseline (82.386 us; speedup 1.0000x reference)
//
#include <hip/hip_runtime.h>
#include <hip/hip_bf16.h>
#include <math.h>

// AttentionBlock3D: b=1, C=256, n=4096, 8 heads x 32 dim, GROUPS=8, EPS=1e-5
//  KA xt_gn:     x f32 [256][4096] -> xTb bf16 [4096][256] + gn partial sums
//  KB fold_all:  stats + fold groupnorm into QKV weights + w_out cast
//  KC gemm_qkv_mfma: qkv = w2b @ x (bf16 MFMA). Outputs:
//                qt[h][pos][32] (Q pre-scaled by LOG2E/sqrt(d)),
//                ktb[h][pos][32], vT[h][32][4096]
//  KD attn_mfma: flash attention, no online max. NEW STRUCTURE (r9):
//                256 blocks x 512 thr; block = 128 queries of one head
//                (h = b&7 -> head's 512KB K/V lives in one XCD L2).
//                8 waves split QUERIES (16 q each, full j range) -> no
//                cross-wave merge. K/V staged per 128-j tile into LDS via
//                global_load_lds (dbuf, 1 barrier/tile, prefetch 1 ahead).
//                LDS XOR-swizzled conflict-free (linear dest + pre-swizzled
//                global src + same-involution read).
//  KE gemm_out_mfma: y = w_outb @ outTb^T + b_out (bf16 MFMA, f32 out)

typedef __attribute__((ext_vector_type(8))) short bf16x8;
typedef __attribute__((ext_vector_type(4))) short bf16x4;
typedef __attribute__((ext_vector_type(4))) float f32x4;
typedef __attribute__((ext_vector_type(4))) unsigned short u16x4;

__device__ inline unsigned short f2bf(float f) {
  __hip_bfloat16 h = __float2bfloat16(f);
  return *reinterpret_cast<unsigned short*>(&h);
}

__device__ inline bf16x4 pack4_bf(float p0, float p1, float p2, float p3) {
  float2 a, b;
  a.x = p0; a.y = p1; b.x = p2; b.y = p3;
  __hip_bfloat162 lo = __float22bfloat162_rn(a);
  __hip_bfloat162 hi = __float22bfloat162_rn(b);
  union U { __hip_bfloat162 h2[2]; bf16x4 v; } u;
  u.h2[0] = lo; u.h2[1] = hi;
  return u.v;
}

__device__ inline void gld_lds16(const void* g, void* l) {
  __builtin_amdgcn_global_load_lds(
      (const __attribute__((address_space(1))) void*)g,
      (__attribute__((address_space(3))) void*)l, 16, 0, 0);
}

// ---------------- KA: transpose + groupnorm partial sums ----------------
__global__ __launch_bounds__(256) void xt_gn_kernel(const float* __restrict__ x,
                                                    unsigned short* __restrict__ xTb,
                                                    float2* __restrict__ psum2) {
  __shared__ float tile[64][65];
  __shared__ float red[4][4];
  int nb = blockIdx.x * 64, cb = blockIdx.y * 64;
  int tn = threadIdx.x & 63, t4 = threadIdx.x >> 6;
  float slo = 0.f, qlo = 0.f, shi = 0.f, qhi = 0.f;
#pragma unroll
  for (int i = 0; i < 16; ++i) {
    int cc = t4 + i * 4;
    float v = x[(size_t)(cb + cc) * 4096 + nb + tn];
    tile[cc][tn] = v;
    if (i < 8) { slo += v; qlo += v * v; } else { shi += v; qhi += v * v; }
  }
#pragma unroll
  for (int off = 32; off > 0; off >>= 1) {
    slo += __shfl_down(slo, off); qlo += __shfl_down(qlo, off);
    shi += __shfl_down(shi, off); qhi += __shfl_down(qhi, off);
  }
  if ((threadIdx.x & 63) == 0) {
    red[t4][0] = slo; red[t4][1] = qlo; red[t4][2] = shi; red[t4][3] = qhi;
  }
  __syncthreads();
  if (threadIdx.x == 0) {
    float a = (red[0][0] + red[1][0]) + (red[2][0] + red[3][0]);
    float b = (red[0][1] + red[1][1]) + (red[2][1] + red[3][1]);
    psum2[(blockIdx.y * 2) * 64 + blockIdx.x] = make_float2(a, b);
  } else if (threadIdx.x == 64) {
    float a = (red[0][2] + red[1][2]) + (red[2][2] + red[3][2]);
    float b = (red[0][3] + red[1][3]) + (red[2][3] + red[3][3]);
    psum2[(blockIdx.y * 2 + 1) * 64 + blockIdx.x] = make_float2(a, b);
  }
#pragma unroll
  for (int i = 0; i < 16; ++i) {
    int nn = t4 + i * 4;
    xTb[(size_t)(nb + nn) * 256 + cb + tn] = f2bf(tile[tn][nn]);
  }
}

// ---------------- KB: stats + fold + w_out cast ----------------
__global__ __launch_bounds__(256) void fold_all_kernel(const float* __restrict__ w_qkv,
                                                       const float* __restrict__ gnw,
                                                       const float* __restrict__ gnb,
                                                       const float2* __restrict__ psum2,
                                                       const float* __restrict__ w_out,
                                                       unsigned short* __restrict__ w2b,
                                                       float* __restrict__ bias0,
                                                       unsigned short* __restrict__ w_outb) {
  int bid = blockIdx.x;
  int t = threadIdx.x;
  if (bid >= 192) {  // w_out -> bf16
    int i = ((bid - 192) * 256 + t) * 4;
    float4 v = *(const float4*)(w_out + i);
    u16x4 o;
    o[0] = f2bf(v.x); o[1] = f2bf(v.y); o[2] = f2bf(v.z); o[3] = f2bf(v.w);
    *(u16x4*)(w_outb + i) = o;
    return;
  }
  __shared__ float sm[8], sr[8];
  __shared__ float s_al[256], s_be[256];
  {
    int g = t >> 5, ii = t & 31;
    float2 p0 = psum2[g * 64 + ii];
    float2 p1 = psum2[g * 64 + 32 + ii];
    float s = p0.x + p1.x, q = p0.y + p1.y;
#pragma unroll
    for (int off = 16; off > 0; off >>= 1) {
      s += __shfl_xor(s, off);
      q += __shfl_xor(q, off);
    }
    if (ii == 0) {
      float mean = s * (1.f / 131072.f);
      float var = q * (1.f / 131072.f) - mean * mean;
      sm[g] = mean;
      sr[g] = rsqrtf(var + 1e-5f);
    }
  }
  __syncthreads();
  {
    int c = t, gg = c >> 5;
    float mean = sm[gg], rstd = sr[gg];
    float al = rstd * gnw[c];
    s_al[c] = al;
    s_be[c] = gnb[c] - mean * al;
  }
  __syncthreads();
  int w = t >> 6, lane = t & 63;
  int row = bid * 4 + w;
  float4 v = *(const float4*)(w_qkv + row * 256 + lane * 4);
  int c0 = lane * 4;
  float part = (v.x * s_be[c0] + v.y * s_be[c0 + 1]) +
               (v.z * s_be[c0 + 2] + v.w * s_be[c0 + 3]);
  u16x4 o;
  o[0] = f2bf(v.x * s_al[c0]);
  o[1] = f2bf(v.y * s_al[c0 + 1]);
  o[2] = f2bf(v.z * s_al[c0 + 2]);
  o[3] = f2bf(v.w * s_al[c0 + 3]);
  *(u16x4*)(w2b + row * 256 + c0) = o;
#pragma unroll
  for (int off = 32; off > 0; off >>= 1) part += __shfl_down(part, off);
  if (lane == 0) bias0[row] = part;
}

// ---------------- KC: qkv GEMM, bf16 MFMA ----------------
__global__ __launch_bounds__(256) void gemm_qkv_mfma(const unsigned short* __restrict__ w2b,
                                                     const unsigned short* __restrict__ xTb,
                                                     const float* __restrict__ bias0,
                                                     unsigned short* __restrict__ qt,
                                                     unsigned short* __restrict__ ktb,
                                                     unsigned short* __restrict__ vT) {
  const int nb = blockIdx.x, mb = blockIdx.y;
  const int t = threadIdx.x;
  const int w = t >> 6, lane = t & 63;
  const int c = lane & 15, g = lane >> 4;
  const int m0 = mb * 64 + w * 16;
  const int n0 = nb * 64;
  const f32x4 zero4 = {0.f, 0.f, 0.f, 0.f};

  const unsigned short* ap = w2b + (size_t)(m0 + c) * 256 + g * 8;
  bf16x8 af[8];
#pragma unroll
  for (int ks = 0; ks < 8; ++ks) af[ks] = *(const bf16x8*)(ap + ks * 32);

  f32x4 acc[4] = {zero4, zero4, zero4, zero4};
  const unsigned short* bp = xTb + (size_t)(n0 + c) * 256 + g * 8;
#pragma unroll
  for (int half = 0; half < 2; ++half) {
    bf16x8 bf[4][4];
#pragma unroll
    for (int nt = 0; nt < 4; ++nt)
#pragma unroll
      for (int k2 = 0; k2 < 4; ++k2)
        bf[nt][k2] = *(const bf16x8*)(bp + (size_t)nt * 4096 + half * 128 + k2 * 32);
#pragma unroll
    for (int k2 = 0; k2 < 4; ++k2)
#pragma unroll
      for (int nt = 0; nt < 4; ++nt)
        acc[nt] = __builtin_amdgcn_mfma_f32_16x16x32_bf16(af[half * 4 + k2], bf[nt][k2],
                                                          acc[nt], 0, 0, 0);
  }

  const int o0 = m0 + g * 4;
  const int t3 = o0 >> 8;
  const int h = (o0 >> 5) & 7;
  const int d0 = o0 & 31;
  float b4[4];
#pragma unroll
  for (int r = 0; r < 4; ++r) b4[r] = bias0[o0 + r];
  // Q pre-scale: 1/sqrt(32) * log2(e) so scores exit QK^T in log2 units
  const float qs = 0.17677669529663687f * 1.4426950408889634f;
#pragma unroll
  for (int nt = 0; nt < 4; ++nt) {
    int n = n0 + nt * 16 + c;
    if (t3 == 0) {
      u16x4 v;
#pragma unroll
      for (int r = 0; r < 4; ++r) v[r] = f2bf((acc[nt][r] + b4[r]) * qs);
      *(u16x4*)(qt + (size_t)(h * 4096 + n) * 32 + d0) = v;
    } else if (t3 == 1) {
      u16x4 v;
#pragma unroll
      for (int r = 0; r < 4; ++r) v[r] = f2bf(acc[nt][r] + b4[r]);
      *(u16x4*)(ktb + (size_t)(h * 4096 + n) * 32 + d0) = v;
    } else {
#pragma unroll
      for (int r = 0; r < 4; ++r)
        vT[(size_t)(h * 32 + d0 + r) * 4096 + n] = f2bf(acc[nt][r] + b4[r]);
    }
  }
}

// ---------------- KD: MFMA flash attention (LDS-staged K/V, i-split) -------
// 256 blocks x 512 thr. h = b&7, i0 = (b>>3)*128. Wave w owns queries
// [i0+w*16, i0+w*16+16), iterates ALL j in 32 tiles of 128.
// K tile LDS [128j][32d] (8KB), V tile LDS [32d][128j] (8KB), double-buffered.
// Swizzles (read XOR == staging-source XOR, both involutions):
//   K: byte ^= ((byte>>7)&3)<<4   (read: ((c>>1)&3)<<4)
//   V: byte ^= ((byte>>8)&7)<<4   (read: ((c&7)<<4))
__global__ __launch_bounds__(512) void attn_mfma_kernel(const unsigned short* __restrict__ qt,
                                                        const unsigned short* __restrict__ ktb,
                                                        const unsigned short* __restrict__ vT,
                                                        unsigned short* __restrict__ outTb) {
  const int b = blockIdx.x;
  const int h = b & 7;
  const int i0 = (b >> 3) * 128;
  const int t = threadIdx.x;
  const int w = t >> 6;
  const int lane = t & 63;
  const int c = lane & 15;
  const int g = lane >> 4;
  const f32x4 zero4 = {0.f, 0.f, 0.f, 0.f};

  __shared__ __align__(16) unsigned short kbuf[2][4096];  // 8KB each
  __shared__ __align__(16) unsigned short vbuf[2][4096];

  // Q fragment: 16 queries per wave, pre-scaled (log2 units)
  const bf16x8 qf = *(const bf16x8*)(qt + (size_t)h * 131072 +
                                     (size_t)(i0 + w * 16 + c) * 32 + g * 8);

  // staging source pointers (bytes), pre-swizzled per thread
  const char* kbase = (const char*)(ktb + (size_t)h * 131072);
  const char* vbase = (const char*)(vT + (size_t)h * 131072);
  const int ksrc = (t * 16) ^ (((t >> 3) & 3) << 4);         // within 8KB tile
  const int vd = t >> 4;                                     // d row 0..31
  const int vsrc = ((t & 15) * 16) ^ ((vd & 7) << 4);        // within 256B row
  char* kdst0 = (char*)&kbuf[0][0] + w * 1024;               // wave-uniform
  char* vdst0 = (char*)&vbuf[0][0] + w * 1024;

  // LDS read offsets (bytes), swizzled
  const int krd_base = c * 64 + g * 16;                      // + js*1024
  const int kswz = ((c >> 1) & 3) << 4;
  const int vswz = (c & 7) << 4;

  f32x4 oacc[2] = {zero4, zero4};
  float l = 0.f;

#define STAGE(bb, tt)                                                     \
  do {                                                                    \
    gld_lds16(kbase + (size_t)(tt) * 8192 + ksrc, kdst0 + (bb) * 8192);   \
    gld_lds16(vbase + (size_t)vd * 8192 + (size_t)(tt) * 256 + vsrc,      \
              vdst0 + (bb) * 8192);                                       \
  } while (0)

  STAGE(0, 0);
  __syncthreads();

  int cur = 0;
#pragma unroll 1
  for (int tt = 0; tt < 32; ++tt) {
    if (tt < 31) STAGE(cur ^ 1, tt + 1);

    const char* kb = (const char*)&kbuf[cur][0];
    const char* vb = (const char*)&vbuf[cur][0];

    // QK^T: st[js] = mfma(K-frag, Q-frag); lane (c,g): S^T[j=js*16+g*4+r][i=c]
    f32x4 st[8];
#pragma unroll
    for (int js = 0; js < 8; ++js) {
      bf16x8 kf = *(const bf16x8*)(kb + ((js * 1024 + krd_base) ^ kswz));
      st[js] = __builtin_amdgcn_mfma_f32_16x16x32_bf16(kf, qf, zero4, 0, 0, 0);
    }

    // softmax (no max; scores in log2 units), RNE pack
    bf16x4 pb[8];
    float lsum = 0.f;
#pragma unroll
    for (int js = 0; js < 8; ++js) {
      float p0 = __builtin_amdgcn_exp2f(st[js][0]);
      float p1 = __builtin_amdgcn_exp2f(st[js][1]);
      float p2 = __builtin_amdgcn_exp2f(st[js][2]);
      float p3 = __builtin_amdgcn_exp2f(st[js][3]);
      lsum += (p0 + p1) + (p2 + p3);
      pb[js] = pack4_bf(p0, p1, p2, p3);
    }
    l += lsum;

    // PV: oacc[dh] += mfma(V-frag, P-frag)
#pragma unroll
    for (int dh = 0; dh < 2; ++dh)
#pragma unroll
      for (int js = 0; js < 8; ++js) {
        bf16x4 vf = *(const bf16x4*)(vb + (((dh * 16 + c) * 256 + js * 32 + g * 8) ^ vswz));
        oacc[dh] = __builtin_amdgcn_mfma_f32_16x16x16bf16_1k(vf, pb[js], oacc[dh], 0, 0, 0);
      }

    __syncthreads();
    cur ^= 1;
  }
#undef STAGE

  // finalize: l summed across the 4 g-lanes holding query i=c
  l += __shfl_xor(l, 16);
  l += __shfl_xor(l, 32);
  float inv = 1.f / l;
#pragma unroll
  for (int dh = 0; dh < 2; ++dh) {
    u16x4 o;
#pragma unroll
    for (int r = 0; r < 4; ++r) o[r] = f2bf(oacc[dh][r] * inv);
    *(u16x4*)(outTb + (size_t)(i0 + w * 16 + c) * 256 + h * 32 + dh * 16 + g * 4) = o;
  }
}

// ---------------- KE: y = w_outb @ outTb^T + b_out (bf16 MFMA) ----------------
__global__ __launch_bounds__(256) void gemm_out_mfma(const unsigned short* __restrict__ w_outb,
                                                     const unsigned short* __restrict__ outTb,
                                                     const float* __restrict__ bias,
                                                     float* __restrict__ y) {
  const int nb = blockIdx.x, mb = blockIdx.y;
  const int t = threadIdx.x;
  const int w = t >> 6, lane = t & 63;
  const int c = lane & 15, g = lane >> 4;
  const int m0 = mb * 64 + w * 16;
  const int n0 = nb * 64;
  const f32x4 zero4 = {0.f, 0.f, 0.f, 0.f};

  const unsigned short* ap = w_outb + (size_t)(m0 + c) * 256 + g * 8;
  bf16x8 af[8];
#pragma unroll
  for (int ks = 0; ks < 8; ++ks) af[ks] = *(const bf16x8*)(ap + ks * 32);

  f32x4 acc[4] = {zero4, zero4, zero4, zero4};
  const unsigned short* bp = outTb + (size_t)(n0 + c) * 256 + g * 8;
#pragma unroll
  for (int half = 0; half < 2; ++half) {
    bf16x8 bf[4][4];
#pragma unroll
    for (int nt = 0; nt < 4; ++nt)
#pragma unroll
      for (int k2 = 0; k2 < 4; ++k2)
        bf[nt][k2] = *(const bf16x8*)(bp + (size_t)nt * 4096 + half * 128 + k2 * 32);
#pragma unroll
    for (int k2 = 0; k2 < 4; ++k2)
#pragma unroll
      for (int nt = 0; nt < 4; ++nt)
        acc[nt] = __builtin_amdgcn_mfma_f32_16x16x32_bf16(af[half * 4 + k2], bf[nt][k2],
                                                          acc[nt], 0, 0, 0);
  }

  const int o0 = m0 + g * 4;
  float b4[4];
#pragma unroll
  for (int r = 0; r < 4; ++r) b4[r] = bias[o0 + r];
#pragma unroll
  for (int nt = 0; nt < 4; ++nt) {
    int n = n0 + nt * 16 + c;
#pragma unroll
    for (int r = 0; r < 4; ++r)
      y[(size_t)(o0 + r) * 4096 + n] = acc[nt][r] + b4[r];
  }
}

extern "C" void kernel_launch(void* const* d_in, const int* in_sizes, int n_in,
                              void* d_out, int out_size, void* d_ws, size_t ws_size,
                              hipStream_t stream) {
  const float* x = (const float*)d_in[0];
  const float* gnw = (const float*)d_in[1];
  const float* gnb = (const float*)d_in[2];
  const float* w_qkv = (const float*)d_in[3];
  const float* w_out = (const float*)d_in[4];
  const float* b_out = (const float*)d_in[5];
  float* ws = (float*)d_ws;

  float2* psum2 = (float2*)ws;                         // 512 float2
  float* bias0 = ws + 1088;                            // 768
  unsigned short* w2b = (unsigned short*)(ws + 2048);  // 768*256 u16
  unsigned short* w_outb = w2b + 196608;               // 256*256 u16
  unsigned short* xTb = w_outb + 65536;                // 4096*256 u16
  unsigned short* qt = xTb + 1048576;                  // 8*4096*32 u16
  unsigned short* ktb = qt + 1048576;
  unsigned short* vT = ktb + 1048576;                  // 8*32*4096 u16
  unsigned short* outTb = vT + 1048576;                // 4096*256 u16
  float* y = (float*)d_out;

  hipLaunchKernelGGL(xt_gn_kernel, dim3(64, 4), dim3(256), 0, stream, x, xTb, psum2);
  hipLaunchKernelGGL(fold_all_kernel, dim3(256), dim3(256), 0, stream, w_qkv, gnw, gnb,
                     psum2, w_out, w2b, bias0, w_outb);
  hipLaunchKernelGGL(gemm_qkv_mfma, dim3(64, 12), dim3(256), 0, stream, w2b, xTb, bias0, qt, ktb, vT);
  hipLaunchKernelGGL(attn_mfma_kernel, dim3(256), dim3(512), 0, stream, qt, ktb, vT, outTb);
  hipLaunchKernelGGL(gemm_out_mfma, dim3(64, 4), dim3(256), 0, stream, w_outb, outTb, b_out, y);
}

// Round 10
// 72.198 us; speedup vs baseline: 1.1411x; 1.1411x over previous
//
#include <hip/hip_runtime.h>
#include <hip/hip_bf16.h>
#include <math.h>

// AttentionBlock3D: b=1, C=256, n=4096, 8 heads x 32 dim, GROUPS=8, EPS=1e-5
//  KA xt_gn:     x f32 [256][4096] -> xTb bf16 [4096][256] + gn partial sums
//  KB fold_all:  stats + fold groupnorm into QKV weights + w_out cast
//  KC gemm_qkv_mfma: qkv = w2b @ x (bf16 MFMA). Outputs qt[h][pos][32]
//                (Q pre-scaled LOG2E/sqrt(d)), ktb[h][pos][32],
//                v16[h][j/16][32][16]
//  KD attn_mfma: r7-verified main loop (38.6us): 512 blocks x 512 thr,
//                64 q/block, 8 waves j-split (512 j each), register-direct
//                K/V streaming (K reg double-buffer), no online max,
//                RNE software pack. r10 change: merge epilogue CHUNKED
//                per i-tile -> LDS 71.7KB -> 19.5KB (r7 was 1 block/CU;
//                now 4 blocks/CU by LDS, 4 by wave cap).
//  KE gemm_out_mfma: y = w_outb @ outTb^T + b_out (bf16 MFMA, f32 out)

typedef __attribute__((ext_vector_type(8))) short bf16x8;
typedef __attribute__((ext_vector_type(4))) short bf16x4;
typedef __attribute__((ext_vector_type(4))) float f32x4;
typedef __attribute__((ext_vector_type(4))) unsigned short u16x4;

__device__ inline unsigned short f2bf(float f) {
  __hip_bfloat16 h = __float2bfloat16(f);
  return *reinterpret_cast<unsigned short*>(&h);
}

__device__ inline bf16x4 pack4_bf(float p0, float p1, float p2, float p3) {
  float2 a, b;
  a.x = p0; a.y = p1; b.x = p2; b.y = p3;
  __hip_bfloat162 lo = __float22bfloat162_rn(a);
  __hip_bfloat162 hi = __float22bfloat162_rn(b);
  union U { __hip_bfloat162 h2[2]; bf16x4 v; } u;
  u.h2[0] = lo; u.h2[1] = hi;
  return u.v;
}

// ---------------- KA: transpose + groupnorm partial sums ----------------
__global__ __launch_bounds__(256) void xt_gn_kernel(const float* __restrict__ x,
                                                    unsigned short* __restrict__ xTb,
                                                    float2* __restrict__ psum2) {
  __shared__ float tile[64][65];
  __shared__ float red[4][4];
  int nb = blockIdx.x * 64, cb = blockIdx.y * 64;
  int tn = threadIdx.x & 63, t4 = threadIdx.x >> 6;
  float slo = 0.f, qlo = 0.f, shi = 0.f, qhi = 0.f;
#pragma unroll
  for (int i = 0; i < 16; ++i) {
    int cc = t4 + i * 4;
    float v = x[(size_t)(cb + cc) * 4096 + nb + tn];
    tile[cc][tn] = v;
    if (i < 8) { slo += v; qlo += v * v; } else { shi += v; qhi += v * v; }
  }
#pragma unroll
  for (int off = 32; off > 0; off >>= 1) {
    slo += __shfl_down(slo, off); qlo += __shfl_down(qlo, off);
    shi += __shfl_down(shi, off); qhi += __shfl_down(qhi, off);
  }
  if ((threadIdx.x & 63) == 0) {
    red[t4][0] = slo; red[t4][1] = qlo; red[t4][2] = shi; red[t4][3] = qhi;
  }
  __syncthreads();
  if (threadIdx.x == 0) {
    float a = (red[0][0] + red[1][0]) + (red[2][0] + red[3][0]);
    float b = (red[0][1] + red[1][1]) + (red[2][1] + red[3][1]);
    psum2[(blockIdx.y * 2) * 64 + blockIdx.x] = make_float2(a, b);
  } else if (threadIdx.x == 64) {
    float a = (red[0][2] + red[1][2]) + (red[2][2] + red[3][2]);
    float b = (red[0][3] + red[1][3]) + (red[2][3] + red[3][3]);
    psum2[(blockIdx.y * 2 + 1) * 64 + blockIdx.x] = make_float2(a, b);
  }
#pragma unroll
  for (int i = 0; i < 16; ++i) {
    int nn = t4 + i * 4;
    xTb[(size_t)(nb + nn) * 256 + cb + tn] = f2bf(tile[tn][nn]);
  }
}

// ---------------- KB: stats + fold + w_out cast ----------------
__global__ __launch_bounds__(256) void fold_all_kernel(const float* __restrict__ w_qkv,
                                                       const float* __restrict__ gnw,
                                                       const float* __restrict__ gnb,
                                                       const float2* __restrict__ psum2,
                                                       const float* __restrict__ w_out,
                                                       unsigned short* __restrict__ w2b,
                                                       float* __restrict__ bias0,
                                                       unsigned short* __restrict__ w_outb) {
  int bid = blockIdx.x;
  int t = threadIdx.x;
  if (bid >= 192) {  // w_out -> bf16
    int i = ((bid - 192) * 256 + t) * 4;
    float4 v = *(const float4*)(w_out + i);
    u16x4 o;
    o[0] = f2bf(v.x); o[1] = f2bf(v.y); o[2] = f2bf(v.z); o[3] = f2bf(v.w);
    *(u16x4*)(w_outb + i) = o;
    return;
  }
  __shared__ float sm[8], sr[8];
  __shared__ float s_al[256], s_be[256];
  {
    int g = t >> 5, ii = t & 31;
    float2 p0 = psum2[g * 64 + ii];
    float2 p1 = psum2[g * 64 + 32 + ii];
    float s = p0.x + p1.x, q = p0.y + p1.y;
#pragma unroll
    for (int off = 16; off > 0; off >>= 1) {
      s += __shfl_xor(s, off);
      q += __shfl_xor(q, off);
    }
    if (ii == 0) {
      float mean = s * (1.f / 131072.f);
      float var = q * (1.f / 131072.f) - mean * mean;
      sm[g] = mean;
      sr[g] = rsqrtf(var + 1e-5f);
    }
  }
  __syncthreads();
  {
    int c = t, gg = c >> 5;
    float mean = sm[gg], rstd = sr[gg];
    float al = rstd * gnw[c];
    s_al[c] = al;
    s_be[c] = gnb[c] - mean * al;
  }
  __syncthreads();
  int w = t >> 6, lane = t & 63;
  int row = bid * 4 + w;
  float4 v = *(const float4*)(w_qkv + row * 256 + lane * 4);
  int c0 = lane * 4;
  float part = (v.x * s_be[c0] + v.y * s_be[c0 + 1]) +
               (v.z * s_be[c0 + 2] + v.w * s_be[c0 + 3]);
  u16x4 o;
  o[0] = f2bf(v.x * s_al[c0]);
  o[1] = f2bf(v.y * s_al[c0 + 1]);
  o[2] = f2bf(v.z * s_al[c0 + 2]);
  o[3] = f2bf(v.w * s_al[c0 + 3]);
  *(u16x4*)(w2b + row * 256 + c0) = o;
#pragma unroll
  for (int off = 32; off > 0; off >>= 1) part += __shfl_down(part, off);
  if (lane == 0) bias0[row] = part;
}

// ---------------- KC: qkv GEMM, bf16 MFMA ----------------
__global__ __launch_bounds__(256) void gemm_qkv_mfma(const unsigned short* __restrict__ w2b,
                                                     const unsigned short* __restrict__ xTb,
                                                     const float* __restrict__ bias0,
                                                     unsigned short* __restrict__ qt,
                                                     unsigned short* __restrict__ ktb,
                                                     unsigned short* __restrict__ v16) {
  const int nb = blockIdx.x, mb = blockIdx.y;
  const int t = threadIdx.x;
  const int w = t >> 6, lane = t & 63;
  const int c = lane & 15, g = lane >> 4;
  const int m0 = mb * 64 + w * 16;
  const int n0 = nb * 64;
  const f32x4 zero4 = {0.f, 0.f, 0.f, 0.f};

  const unsigned short* ap = w2b + (size_t)(m0 + c) * 256 + g * 8;
  bf16x8 af[8];
#pragma unroll
  for (int ks = 0; ks < 8; ++ks) af[ks] = *(const bf16x8*)(ap + ks * 32);

  f32x4 acc[4] = {zero4, zero4, zero4, zero4};
  const unsigned short* bp = xTb + (size_t)(n0 + c) * 256 + g * 8;
#pragma unroll
  for (int half = 0; half < 2; ++half) {
    bf16x8 bf[4][4];
#pragma unroll
    for (int nt = 0; nt < 4; ++nt)
#pragma unroll
      for (int k2 = 0; k2 < 4; ++k2)
        bf[nt][k2] = *(const bf16x8*)(bp + (size_t)nt * 4096 + half * 128 + k2 * 32);
#pragma unroll
    for (int k2 = 0; k2 < 4; ++k2)
#pragma unroll
      for (int nt = 0; nt < 4; ++nt)
        acc[nt] = __builtin_amdgcn_mfma_f32_16x16x32_bf16(af[half * 4 + k2], bf[nt][k2],
                                                          acc[nt], 0, 0, 0);
  }

  const int o0 = m0 + g * 4;
  const int t3 = o0 >> 8;
  const int h = (o0 >> 5) & 7;
  const int d0 = o0 & 31;
  float b4[4];
#pragma unroll
  for (int r = 0; r < 4; ++r) b4[r] = bias0[o0 + r];
  // Q pre-scale: 1/sqrt(32) * log2(e) so scores exit QK^T in log2 units
  const float qs = 0.17677669529663687f * 1.4426950408889634f;
#pragma unroll
  for (int nt = 0; nt < 4; ++nt) {
    int n = n0 + nt * 16 + c;
    if (t3 == 0) {
      u16x4 v;
#pragma unroll
      for (int r = 0; r < 4; ++r) v[r] = f2bf((acc[nt][r] + b4[r]) * qs);
      *(u16x4*)(qt + (size_t)(h * 4096 + n) * 32 + d0) = v;
    } else if (t3 == 1) {
      u16x4 v;
#pragma unroll
      for (int r = 0; r < 4; ++r) v[r] = f2bf(acc[nt][r] + b4[r]);
      *(u16x4*)(ktb + (size_t)(h * 4096 + n) * 32 + d0) = v;
    } else {
#pragma unroll
      for (int r = 0; r < 4; ++r)
        v16[(size_t)((h * 256 + (n >> 4)) * 32 + d0 + r) * 16 + (n & 15)] =
            f2bf(acc[nt][r] + b4[r]);
    }
  }
}

// ---------------- KD: MFMA flash attention, no online max ----------------
// 512 blocks x 512 threads: h = b&7 (XCD affinity), i0 = (b>>3)*64.
// 8 waves split j (512 each), barrier-free main loop, K reg double-buffer,
// V issued early. r10: merge chunked per i-tile (LDS ~19.5KB -> 4 blocks/CU).
__global__ __launch_bounds__(512) void attn_mfma_kernel(const unsigned short* __restrict__ qt,
                                                        const unsigned short* __restrict__ ktb,
                                                        const unsigned short* __restrict__ v16,
                                                        unsigned short* __restrict__ outTb) {
  const int b = blockIdx.x;
  const int h = b & 7;
  const int i0 = (b >> 3) * 64;
  const int t = threadIdx.x;
  const int w = t >> 6;
  const int lane = t & 63;
  const int c = lane & 15;
  const int g = lane >> 4;
  const f32x4 zero4 = {0.f, 0.f, 0.f, 0.f};

  const unsigned short* qb = qt + (size_t)h * 131072 + (size_t)(i0 + c) * 32 + g * 8;
  bf16x8 qf[4];
#pragma unroll
  for (int it = 0; it < 4; ++it) qf[it] = *(const bf16x8*)(qb + it * 512);

  const unsigned short* kp = ktb + (size_t)h * 131072 + (size_t)(w * 512 + c) * 32 + g * 8;
  const unsigned short* vp = v16 + (size_t)((h * 256 + w * 32) * 32 + c) * 16 + g * 4;

  float l[4] = {0.f, 0.f, 0.f, 0.f};
  f32x4 oacc[4][2];
#pragma unroll
  for (int it = 0; it < 4; ++it) {
    oacc[it][0] = zero4;
    oacc[it][1] = zero4;
  }

  bf16x8 kf[4], kn[4];
#pragma unroll
  for (int js = 0; js < 4; ++js) kf[js] = *(const bf16x8*)(kp + js * 512);

#pragma unroll 1
  for (int jt = 0; jt < 8; ++jt) {
    bf16x4 vf[2][4];
#pragma unroll
    for (int dh = 0; dh < 2; ++dh)
#pragma unroll
      for (int js = 0; js < 4; ++js)
        vf[dh][js] = *(const bf16x4*)(vp + (jt * 4 + js) * 512 + dh * 256);
    int jn = (jt < 7) ? jt + 1 : 7;
#pragma unroll
    for (int js = 0; js < 4; ++js)
      kn[js] = *(const bf16x8*)(kp + jn * 2048 + js * 512);

#pragma unroll
    for (int it = 0; it < 4; ++it) {
      f32x4 st[4];
      __builtin_amdgcn_s_setprio(1);
#pragma unroll
      for (int js = 0; js < 4; ++js)
        st[js] = __builtin_amdgcn_mfma_f32_16x16x32_bf16(kf[js], qf[it], zero4, 0, 0, 0);
      __builtin_amdgcn_s_setprio(0);
      bf16x4 pb[4];
      float lsum = 0.f;
#pragma unroll
      for (int js = 0; js < 4; ++js) {
        // scores already in log2 units (Q pre-scaled by LOG2E/sqrt(d))
        float p0 = __builtin_amdgcn_exp2f(st[js][0]);
        float p1 = __builtin_amdgcn_exp2f(st[js][1]);
        float p2 = __builtin_amdgcn_exp2f(st[js][2]);
        float p3 = __builtin_amdgcn_exp2f(st[js][3]);
        lsum += (p0 + p1) + (p2 + p3);
        pb[js] = pack4_bf(p0, p1, p2, p3);
      }
      l[it] += lsum;
      __builtin_amdgcn_s_setprio(1);
#pragma unroll
      for (int js = 0; js < 4; ++js) {
        oacc[it][0] = __builtin_amdgcn_mfma_f32_16x16x16bf16_1k(vf[0][js], pb[js], oacc[it][0], 0, 0, 0);
        oacc[it][1] = __builtin_amdgcn_mfma_f32_16x16x16bf16_1k(vf[1][js], pb[js], oacc[it][1], 0, 0, 0);
      }
      __builtin_amdgcn_s_setprio(0);
    }
#pragma unroll
    for (int js = 0; js < 4; ++js) kf[js] = kn[js];
  }

  // ---- merge 8 waves' partials, chunked per i-tile (LDS ~19.5KB) ----
  __shared__ float lds_o[8][2][4][4][17];  // [w][dh][g][r][c] (one i-tile)
  __shared__ float lds_l[8][4][16];
#pragma unroll
  for (int it = 0; it < 4; ++it) {
    float lv = l[it];
    lv += __shfl_xor(lv, 16);
    lv += __shfl_xor(lv, 32);
    if (g == 0) lds_l[w][it][c] = lv;
  }
#pragma unroll 1
  for (int itc = 0; itc < 4; ++itc) {
#pragma unroll
    for (int dh = 0; dh < 2; ++dh)
#pragma unroll
      for (int r = 0; r < 4; ++r)
        lds_o[w][dh][g][r][c] = oacc[itc][dh][r];
    __syncthreads();
    if (w < 2) {
      const int dh = w;
      float L = ((lds_l[0][itc][c] + lds_l[1][itc][c]) + (lds_l[2][itc][c] + lds_l[3][itc][c])) +
                ((lds_l[4][itc][c] + lds_l[5][itc][c]) + (lds_l[6][itc][c] + lds_l[7][itc][c]));
      float inv = 1.f / L;
      u16x4 o;
#pragma unroll
      for (int r = 0; r < 4; ++r) {
        float v = ((lds_o[0][dh][g][r][c] + lds_o[1][dh][g][r][c]) +
                   (lds_o[2][dh][g][r][c] + lds_o[3][dh][g][r][c])) +
                  ((lds_o[4][dh][g][r][c] + lds_o[5][dh][g][r][c]) +
                   (lds_o[6][dh][g][r][c] + lds_o[7][dh][g][r][c]));
        o[r] = f2bf(v * inv);
      }
      *(u16x4*)(outTb + (size_t)(i0 + itc * 16 + c) * 256 + h * 32 + dh * 16 + g * 4) = o;
    }
    __syncthreads();
  }
}

// ---------------- KE: y = w_outb @ outTb^T + b_out (bf16 MFMA) ----------------
__global__ __launch_bounds__(256) void gemm_out_mfma(const unsigned short* __restrict__ w_outb,
                                                     const unsigned short* __restrict__ outTb,
                                                     const float* __restrict__ bias,
                                                     float* __restrict__ y) {
  const int nb = blockIdx.x, mb = blockIdx.y;
  const int t = threadIdx.x;
  const int w = t >> 6, lane = t & 63;
  const int c = lane & 15, g = lane >> 4;
  const int m0 = mb * 64 + w * 16;
  const int n0 = nb * 64;
  const f32x4 zero4 = {0.f, 0.f, 0.f, 0.f};

  const unsigned short* ap = w_outb + (size_t)(m0 + c) * 256 + g * 8;
  bf16x8 af[8];
#pragma unroll
  for (int ks = 0; ks < 8; ++ks) af[ks] = *(const bf16x8*)(ap + ks * 32);

  f32x4 acc[4] = {zero4, zero4, zero4, zero4};
  const unsigned short* bp = outTb + (size_t)(n0 + c) * 256 + g * 8;
#pragma unroll
  for (int half = 0; half < 2; ++half) {
    bf16x8 bf[4][4];
#pragma unroll
    for (int nt = 0; nt < 4; ++nt)
#pragma unroll
      for (int k2 = 0; k2 < 4; ++k2)
        bf[nt][k2] = *(const bf16x8*)(bp + (size_t)nt * 4096 + half * 128 + k2 * 32);
#pragma unroll
    for (int k2 = 0; k2 < 4; ++k2)
#pragma unroll
      for (int nt = 0; nt < 4; ++nt)
        acc[nt] = __builtin_amdgcn_mfma_f32_16x16x32_bf16(af[half * 4 + k2], bf[nt][k2],
                                                          acc[nt], 0, 0, 0);
  }

  const int o0 = m0 + g * 4;
  float b4[4];
#pragma unroll
  for (int r = 0; r < 4; ++r) b4[r] = bias[o0 + r];
#pragma unroll
  for (int nt = 0; nt < 4; ++nt) {
    int n = n0 + nt * 16 + c;
#pragma unroll
    for (int r = 0; r < 4; ++r)
      y[(size_t)(o0 + r) * 4096 + n] = acc[nt][r] + b4[r];
  }
}

extern "C" void kernel_launch(void* const* d_in, const int* in_sizes, int n_in,
                              void* d_out, int out_size, void* d_ws, size_t ws_size,
                              hipStream_t stream) {
  const float* x = (const float*)d_in[0];
  const float* gnw = (const float*)d_in[1];
  const float* gnb = (const float*)d_in[2];
  const float* w_qkv = (const float*)d_in[3];
  const float* w_out = (const float*)d_in[4];
  const float* b_out = (const float*)d_in[5];
  float* ws = (float*)d_ws;

  float2* psum2 = (float2*)ws;                         // 512 float2
  float* bias0 = ws + 1088;                            // 768
  unsigned short* w2b = (unsigned short*)(ws + 2048);  // 768*256 u16
  unsigned short* w_outb = w2b + 196608;               // 256*256 u16
  unsigned short* xTb = w_outb + 65536;                // 4096*256 u16
  unsigned short* qt = xTb + 1048576;                  // 8*4096*32 u16
  unsigned short* ktb = qt + 1048576;
  unsigned short* v16 = ktb + 1048576;                 // tiled V
  unsigned short* outTb = v16 + 1048576;               // 4096*256 u16
  float* y = (float*)d_out;

  hipLaunchKernelGGL(xt_gn_kernel, dim3(64, 4), dim3(256), 0, stream, x, xTb, psum2);
  hipLaunchKernelGGL(fold_all_kernel, dim3(256), dim3(256), 0, stream, w_qkv, gnw, gnb,
                     psum2, w_out, w2b, bias0, w_outb);
  hipLaunchKernelGGL(gemm_qkv_mfma, dim3(64, 12), dim3(256), 0, stream, w2b, xTb, bias0, qt, ktb, v16);
  hipLaunchKernelGGL(attn_mfma_kernel, dim3(512), dim3(512), 0, stream, qt, ktb, v16, outTb);
  hipLaunchKernelGGL(gemm_out_mfma, dim3(64, 4), dim3(256), 0, stream, w_outb, outTb, b_out, y);
}

// Round 11
// 71.538 us; speedup vs baseline: 1.1516x; 1.0092x over previous
//
#include <hip/hip_runtime.h>
#include <hip/hip_bf16.h>
#include <math.h>

// AttentionBlock3D: b=1, C=256, n=4096, 8 heads x 32 dim, GROUPS=8, EPS=1e-5
//  KA xt_gn:     x f32 [256][4096] -> xTb bf16 [4096][256] + gn partial sums
//  KB fold_all:  stats + fold groupnorm into QKV weights + w_out cast
//  KC gemm_qkv_mfma: qkv = w2b @ x (bf16 MFMA). Outputs qt[h][pos][32]
//                (Q pre-scaled LOG2E/sqrt(d)), ktb[h][pos][32],
//                v16[h][j/16][32][16]
//  KD attn_mfma: r7/r10 main loop, 512 blocks x 512 thr, 64 q/block,
//                8 waves j-split, no online max, RNE pack, chunked merge.
//                r11 change (scheduling only): __launch_bounds__(512,1) to
//                un-starve the register allocator (r10 got 72 VGPR -> no
//                ILP), jt-loop unrolled x2 with two full K+V register sets
//                (true 1-tile-ahead prefetch of BOTH K and V, no reg copies).
//  KE gemm_out_mfma: y = w_outb @ outTb^T + b_out (bf16 MFMA, f32 out)

typedef __attribute__((ext_vector_type(8))) short bf16x8;
typedef __attribute__((ext_vector_type(4))) short bf16x4;
typedef __attribute__((ext_vector_type(4))) float f32x4;
typedef __attribute__((ext_vector_type(4))) unsigned short u16x4;

__device__ inline unsigned short f2bf(float f) {
  __hip_bfloat16 h = __float2bfloat16(f);
  return *reinterpret_cast<unsigned short*>(&h);
}

__device__ inline bf16x4 pack4_bf(float p0, float p1, float p2, float p3) {
  float2 a, b;
  a.x = p0; a.y = p1; b.x = p2; b.y = p3;
  __hip_bfloat162 lo = __float22bfloat162_rn(a);
  __hip_bfloat162 hi = __float22bfloat162_rn(b);
  union U { __hip_bfloat162 h2[2]; bf16x4 v; } u;
  u.h2[0] = lo; u.h2[1] = hi;
  return u.v;
}

// ---------------- KA: transpose + groupnorm partial sums ----------------
__global__ __launch_bounds__(256) void xt_gn_kernel(const float* __restrict__ x,
                                                    unsigned short* __restrict__ xTb,
                                                    float2* __restrict__ psum2) {
  __shared__ float tile[64][65];
  __shared__ float red[4][4];
  int nb = blockIdx.x * 64, cb = blockIdx.y * 64;
  int tn = threadIdx.x & 63, t4 = threadIdx.x >> 6;
  float slo = 0.f, qlo = 0.f, shi = 0.f, qhi = 0.f;
#pragma unroll
  for (int i = 0; i < 16; ++i) {
    int cc = t4 + i * 4;
    float v = x[(size_t)(cb + cc) * 4096 + nb + tn];
    tile[cc][tn] = v;
    if (i < 8) { slo += v; qlo += v * v; } else { shi += v; qhi += v * v; }
  }
#pragma unroll
  for (int off = 32; off > 0; off >>= 1) {
    slo += __shfl_down(slo, off); qlo += __shfl_down(qlo, off);
    shi += __shfl_down(shi, off); qhi += __shfl_down(qhi, off);
  }
  if ((threadIdx.x & 63) == 0) {
    red[t4][0] = slo; red[t4][1] = qlo; red[t4][2] = shi; red[t4][3] = qhi;
  }
  __syncthreads();
  if (threadIdx.x == 0) {
    float a = (red[0][0] + red[1][0]) + (red[2][0] + red[3][0]);
    float b = (red[0][1] + red[1][1]) + (red[2][1] + red[3][1]);
    psum2[(blockIdx.y * 2) * 64 + blockIdx.x] = make_float2(a, b);
  } else if (threadIdx.x == 64) {
    float a = (red[0][2] + red[1][2]) + (red[2][2] + red[3][2]);
    float b = (red[0][3] + red[1][3]) + (red[2][3] + red[3][3]);
    psum2[(blockIdx.y * 2 + 1) * 64 + blockIdx.x] = make_float2(a, b);
  }
#pragma unroll
  for (int i = 0; i < 16; ++i) {
    int nn = t4 + i * 4;
    xTb[(size_t)(nb + nn) * 256 + cb + tn] = f2bf(tile[tn][nn]);
  }
}

// ---------------- KB: stats + fold + w_out cast ----------------
__global__ __launch_bounds__(256) void fold_all_kernel(const float* __restrict__ w_qkv,
                                                       const float* __restrict__ gnw,
                                                       const float* __restrict__ gnb,
                                                       const float2* __restrict__ psum2,
                                                       const float* __restrict__ w_out,
                                                       unsigned short* __restrict__ w2b,
                                                       float* __restrict__ bias0,
                                                       unsigned short* __restrict__ w_outb) {
  int bid = blockIdx.x;
  int t = threadIdx.x;
  if (bid >= 192) {  // w_out -> bf16
    int i = ((bid - 192) * 256 + t) * 4;
    float4 v = *(const float4*)(w_out + i);
    u16x4 o;
    o[0] = f2bf(v.x); o[1] = f2bf(v.y); o[2] = f2bf(v.z); o[3] = f2bf(v.w);
    *(u16x4*)(w_outb + i) = o;
    return;
  }
  __shared__ float sm[8], sr[8];
  __shared__ float s_al[256], s_be[256];
  {
    int g = t >> 5, ii = t & 31;
    float2 p0 = psum2[g * 64 + ii];
    float2 p1 = psum2[g * 64 + 32 + ii];
    float s = p0.x + p1.x, q = p0.y + p1.y;
#pragma unroll
    for (int off = 16; off > 0; off >>= 1) {
      s += __shfl_xor(s, off);
      q += __shfl_xor(q, off);
    }
    if (ii == 0) {
      float mean = s * (1.f / 131072.f);
      float var = q * (1.f / 131072.f) - mean * mean;
      sm[g] = mean;
      sr[g] = rsqrtf(var + 1e-5f);
    }
  }
  __syncthreads();
  {
    int c = t, gg = c >> 5;
    float mean = sm[gg], rstd = sr[gg];
    float al = rstd * gnw[c];
    s_al[c] = al;
    s_be[c] = gnb[c] - mean * al;
  }
  __syncthreads();
  int w = t >> 6, lane = t & 63;
  int row = bid * 4 + w;
  float4 v = *(const float4*)(w_qkv + row * 256 + lane * 4);
  int c0 = lane * 4;
  float part = (v.x * s_be[c0] + v.y * s_be[c0 + 1]) +
               (v.z * s_be[c0 + 2] + v.w * s_be[c0 + 3]);
  u16x4 o;
  o[0] = f2bf(v.x * s_al[c0]);
  o[1] = f2bf(v.y * s_al[c0 + 1]);
  o[2] = f2bf(v.z * s_al[c0 + 2]);
  o[3] = f2bf(v.w * s_al[c0 + 3]);
  *(u16x4*)(w2b + row * 256 + c0) = o;
#pragma unroll
  for (int off = 32; off > 0; off >>= 1) part += __shfl_down(part, off);
  if (lane == 0) bias0[row] = part;
}

// ---------------- KC: qkv GEMM, bf16 MFMA ----------------
__global__ __launch_bounds__(256) void gemm_qkv_mfma(const unsigned short* __restrict__ w2b,
                                                     const unsigned short* __restrict__ xTb,
                                                     const float* __restrict__ bias0,
                                                     unsigned short* __restrict__ qt,
                                                     unsigned short* __restrict__ ktb,
                                                     unsigned short* __restrict__ v16) {
  const int nb = blockIdx.x, mb = blockIdx.y;
  const int t = threadIdx.x;
  const int w = t >> 6, lane = t & 63;
  const int c = lane & 15, g = lane >> 4;
  const int m0 = mb * 64 + w * 16;
  const int n0 = nb * 64;
  const f32x4 zero4 = {0.f, 0.f, 0.f, 0.f};

  const unsigned short* ap = w2b + (size_t)(m0 + c) * 256 + g * 8;
  bf16x8 af[8];
#pragma unroll
  for (int ks = 0; ks < 8; ++ks) af[ks] = *(const bf16x8*)(ap + ks * 32);

  f32x4 acc[4] = {zero4, zero4, zero4, zero4};
  const unsigned short* bp = xTb + (size_t)(n0 + c) * 256 + g * 8;
#pragma unroll
  for (int half = 0; half < 2; ++half) {
    bf16x8 bf[4][4];
#pragma unroll
    for (int nt = 0; nt < 4; ++nt)
#pragma unroll
      for (int k2 = 0; k2 < 4; ++k2)
        bf[nt][k2] = *(const bf16x8*)(bp + (size_t)nt * 4096 + half * 128 + k2 * 32);
#pragma unroll
    for (int k2 = 0; k2 < 4; ++k2)
#pragma unroll
      for (int nt = 0; nt < 4; ++nt)
        acc[nt] = __builtin_amdgcn_mfma_f32_16x16x32_bf16(af[half * 4 + k2], bf[nt][k2],
                                                          acc[nt], 0, 0, 0);
  }

  const int o0 = m0 + g * 4;
  const int t3 = o0 >> 8;
  const int h = (o0 >> 5) & 7;
  const int d0 = o0 & 31;
  float b4[4];
#pragma unroll
  for (int r = 0; r < 4; ++r) b4[r] = bias0[o0 + r];
  // Q pre-scale: 1/sqrt(32) * log2(e) so scores exit QK^T in log2 units
  const float qs = 0.17677669529663687f * 1.4426950408889634f;
#pragma unroll
  for (int nt = 0; nt < 4; ++nt) {
    int n = n0 + nt * 16 + c;
    if (t3 == 0) {
      u16x4 v;
#pragma unroll
      for (int r = 0; r < 4; ++r) v[r] = f2bf((acc[nt][r] + b4[r]) * qs);
      *(u16x4*)(qt + (size_t)(h * 4096 + n) * 32 + d0) = v;
    } else if (t3 == 1) {
      u16x4 v;
#pragma unroll
      for (int r = 0; r < 4; ++r) v[r] = f2bf(acc[nt][r] + b4[r]);
      *(u16x4*)(ktb + (size_t)(h * 4096 + n) * 32 + d0) = v;
    } else {
#pragma unroll
      for (int r = 0; r < 4; ++r)
        v16[(size_t)((h * 256 + (n >> 4)) * 32 + d0 + r) * 16 + (n & 15)] =
            f2bf(acc[nt][r] + b4[r]);
    }
  }
}

// ---------------- KD: MFMA flash attention, no online max ----------------
// One (jt, it) compute step over a 64j x 16q tile pair set. Shared by both
// unrolled pipeline stages.
__device__ __forceinline__ void attn_step(const bf16x8* kf, const bf16x4 vf[2][4],
                                          const bf16x8* qf, f32x4 (*oacc)[2],
                                          float* l) {
  const f32x4 zero4 = {0.f, 0.f, 0.f, 0.f};
#pragma unroll
  for (int it = 0; it < 4; ++it) {
    f32x4 st[4];
    __builtin_amdgcn_s_setprio(1);
#pragma unroll
    for (int js = 0; js < 4; ++js)
      st[js] = __builtin_amdgcn_mfma_f32_16x16x32_bf16(kf[js], qf[it], zero4, 0, 0, 0);
    __builtin_amdgcn_s_setprio(0);
    bf16x4 pb[4];
    float lsum = 0.f;
#pragma unroll
    for (int js = 0; js < 4; ++js) {
      // scores already in log2 units (Q pre-scaled by LOG2E/sqrt(d))
      float p0 = __builtin_amdgcn_exp2f(st[js][0]);
      float p1 = __builtin_amdgcn_exp2f(st[js][1]);
      float p2 = __builtin_amdgcn_exp2f(st[js][2]);
      float p3 = __builtin_amdgcn_exp2f(st[js][3]);
      lsum += (p0 + p1) + (p2 + p3);
      pb[js] = pack4_bf(p0, p1, p2, p3);
    }
    l[it] += lsum;
    __builtin_amdgcn_s_setprio(1);
#pragma unroll
    for (int js = 0; js < 4; ++js) {
      oacc[it][0] = __builtin_amdgcn_mfma_f32_16x16x16bf16_1k(vf[0][js], pb[js], oacc[it][0], 0, 0, 0);
      oacc[it][1] = __builtin_amdgcn_mfma_f32_16x16x16bf16_1k(vf[1][js], pb[js], oacc[it][1], 0, 0, 0);
    }
    __builtin_amdgcn_s_setprio(0);
  }
}

// 512 blocks x 512 threads: h = b&7 (XCD affinity), i0 = (b>>3)*64.
// 8 waves split j (512 each). r11: (512,1) launch bounds + 2x-unrolled jt
// pipeline with two K+V register sets (true 1-ahead prefetch, no copies).
__global__ __launch_bounds__(512, 1) void attn_mfma_kernel(const unsigned short* __restrict__ qt,
                                                           const unsigned short* __restrict__ ktb,
                                                           const unsigned short* __restrict__ v16,
                                                           unsigned short* __restrict__ outTb) {
  const int b = blockIdx.x;
  const int h = b & 7;
  const int i0 = (b >> 3) * 64;
  const int t = threadIdx.x;
  const int w = t >> 6;
  const int lane = t & 63;
  const int c = lane & 15;
  const int g = lane >> 4;
  const f32x4 zero4 = {0.f, 0.f, 0.f, 0.f};

  const unsigned short* qb = qt + (size_t)h * 131072 + (size_t)(i0 + c) * 32 + g * 8;
  bf16x8 qf[4];
#pragma unroll
  for (int it = 0; it < 4; ++it) qf[it] = *(const bf16x8*)(qb + it * 512);

  const unsigned short* kp = ktb + (size_t)h * 131072 + (size_t)(w * 512 + c) * 32 + g * 8;
  const unsigned short* vp = v16 + (size_t)((h * 256 + w * 32) * 32 + c) * 16 + g * 4;

  float l[4] = {0.f, 0.f, 0.f, 0.f};
  f32x4 oacc[4][2];
#pragma unroll
  for (int it = 0; it < 4; ++it) {
    oacc[it][0] = zero4;
    oacc[it][1] = zero4;
  }

#define KLOAD(dst, tt)                                         \
  _Pragma("unroll") for (int js = 0; js < 4; ++js)             \
      dst[js] = *(const bf16x8*)(kp + (tt) * 2048 + js * 512);
#define VLOAD(dst, tt)                                                        \
  _Pragma("unroll") for (int dh = 0; dh < 2; ++dh)                            \
      _Pragma("unroll") for (int js = 0; js < 4; ++js)                        \
          dst[dh][js] = *(const bf16x4*)(vp + ((tt) * 4 + js) * 512 + dh * 256);

  bf16x8 kfA[4], kfB[4];
  bf16x4 vfA[2][4], vfB[2][4];
  KLOAD(kfA, 0);
  VLOAD(vfA, 0);

#pragma unroll 1
  for (int jt2 = 0; jt2 < 4; ++jt2) {
    const int base = jt2 * 2;
    KLOAD(kfB, base + 1);
    VLOAD(vfB, base + 1);
    attn_step(kfA, vfA, qf, oacc, l);
    if (jt2 < 3) {
      KLOAD(kfA, base + 2);
      VLOAD(vfA, base + 2);
    }
    attn_step(kfB, vfB, qf, oacc, l);
  }
#undef KLOAD
#undef VLOAD

  // ---- merge 8 waves' partials, chunked per i-tile (LDS ~19.5KB) ----
  __shared__ float lds_o[8][2][4][4][17];  // [w][dh][g][r][c] (one i-tile)
  __shared__ float lds_l[8][4][16];
#pragma unroll
  for (int it = 0; it < 4; ++it) {
    float lv = l[it];
    lv += __shfl_xor(lv, 16);
    lv += __shfl_xor(lv, 32);
    if (g == 0) lds_l[w][it][c] = lv;
  }
#pragma unroll 1
  for (int itc = 0; itc < 4; ++itc) {
#pragma unroll
    for (int dh = 0; dh < 2; ++dh)
#pragma unroll
      for (int r = 0; r < 4; ++r)
        lds_o[w][dh][g][r][c] = oacc[itc][dh][r];
    __syncthreads();
    if (w < 2) {
      const int dh = w;
      float L = ((lds_l[0][itc][c] + lds_l[1][itc][c]) + (lds_l[2][itc][c] + lds_l[3][itc][c])) +
                ((lds_l[4][itc][c] + lds_l[5][itc][c]) + (lds_l[6][itc][c] + lds_l[7][itc][c]));
      float inv = 1.f / L;
      u16x4 o;
#pragma unroll
      for (int r = 0; r < 4; ++r) {
        float v = ((lds_o[0][dh][g][r][c] + lds_o[1][dh][g][r][c]) +
                   (lds_o[2][dh][g][r][c] + lds_o[3][dh][g][r][c])) +
                  ((lds_o[4][dh][g][r][c] + lds_o[5][dh][g][r][c]) +
                   (lds_o[6][dh][g][r][c] + lds_o[7][dh][g][r][c]));
        o[r] = f2bf(v * inv);
      }
      *(u16x4*)(outTb + (size_t)(i0 + itc * 16 + c) * 256 + h * 32 + dh * 16 + g * 4) = o;
    }
    __syncthreads();
  }
}

// ---------------- KE: y = w_outb @ outTb^T + b_out (bf16 MFMA) ----------------
__global__ __launch_bounds__(256) void gemm_out_mfma(const unsigned short* __restrict__ w_outb,
                                                     const unsigned short* __restrict__ outTb,
                                                     const float* __restrict__ bias,
                                                     float* __restrict__ y) {
  const int nb = blockIdx.x, mb = blockIdx.y;
  const int t = threadIdx.x;
  const int w = t >> 6, lane = t & 63;
  const int c = lane & 15, g = lane >> 4;
  const int m0 = mb * 64 + w * 16;
  const int n0 = nb * 64;
  const f32x4 zero4 = {0.f, 0.f, 0.f, 0.f};

  const unsigned short* ap = w_outb + (size_t)(m0 + c) * 256 + g * 8;
  bf16x8 af[8];
#pragma unroll
  for (int ks = 0; ks < 8; ++ks) af[ks] = *(const bf16x8*)(ap + ks * 32);

  f32x4 acc[4] = {zero4, zero4, zero4, zero4};
  const unsigned short* bp = outTb + (size_t)(n0 + c) * 256 + g * 8;
#pragma unroll
  for (int half = 0; half < 2; ++half) {
    bf16x8 bf[4][4];
#pragma unroll
    for (int nt = 0; nt < 4; ++nt)
#pragma unroll
      for (int k2 = 0; k2 < 4; ++k2)
        bf[nt][k2] = *(const bf16x8*)(bp + (size_t)nt * 4096 + half * 128 + k2 * 32);
#pragma unroll
    for (int k2 = 0; k2 < 4; ++k2)
#pragma unroll
      for (int nt = 0; nt < 4; ++nt)
        acc[nt] = __builtin_amdgcn_mfma_f32_16x16x32_bf16(af[half * 4 + k2], bf[nt][k2],
                                                          acc[nt], 0, 0, 0);
  }

  const int o0 = m0 + g * 4;
  float b4[4];
#pragma unroll
  for (int r = 0; r < 4; ++r) b4[r] = bias[o0 + r];
#pragma unroll
  for (int nt = 0; nt < 4; ++nt) {
    int n = n0 + nt * 16 + c;
#pragma unroll
    for (int r = 0; r < 4; ++r)
      y[(size_t)(o0 + r) * 4096 + n] = acc[nt][r] + b4[r];
  }
}

extern "C" void kernel_launch(void* const* d_in, const int* in_sizes, int n_in,
                              void* d_out, int out_size, void* d_ws, size_t ws_size,
                              hipStream_t stream) {
  const float* x = (const float*)d_in[0];
  const float* gnw = (const float*)d_in[1];
  const float* gnb = (const float*)d_in[2];
  const float* w_qkv = (const float*)d_in[3];
  const float* w_out = (const float*)d_in[4];
  const float* b_out = (const float*)d_in[5];
  float* ws = (float*)d_ws;

  float2* psum2 = (float2*)ws;                         // 512 float2
  float* bias0 = ws + 1088;                            // 768
  unsigned short* w2b = (unsigned short*)(ws + 2048);  // 768*256 u16
  unsigned short* w_outb = w2b + 196608;               // 256*256 u16
  unsigned short* xTb = w_outb + 65536;                // 4096*256 u16
  unsigned short* qt = xTb + 1048576;                  // 8*4096*32 u16
  unsigned short* ktb = qt + 1048576;
  unsigned short* v16 = ktb + 1048576;                 // tiled V
  unsigned short* outTb = v16 + 1048576;               // 4096*256 u16
  float* y = (float*)d_out;

  hipLaunchKernelGGL(xt_gn_kernel, dim3(64, 4), dim3(256), 0, stream, x, xTb, psum2);
  hipLaunchKernelGGL(fold_all_kernel, dim3(256), dim3(256), 0, stream, w_qkv, gnw, gnb,
                     psum2, w_out, w2b, bias0, w_outb);
  hipLaunchKernelGGL(gemm_qkv_mfma, dim3(64, 12), dim3(256), 0, stream, w2b, xTb, bias0, qt, ktb, v16);
  hipLaunchKernelGGL(attn_mfma_kernel, dim3(512), dim3(512), 0, stream, qt, ktb, v16, outTb);
  hipLaunchKernelGGL(gemm_out_mfma, dim3(64, 4), dim3(256), 0, stream, w_outb, outTb, b_out, y);
}

// Round 12
// 68.579 us; speedup vs baseline: 1.2013x; 1.0432x over previous
//
#include <hip/hip_runtime.h>
#include <hip/hip_bf16.h>
#include <math.h>

// AttentionBlock3D: b=1, C=256, n=4096, 8 heads x 32 dim, GROUPS=8, EPS=1e-5
//  KA xt_gn:     x f32 [256][4096] -> xTb bf16 [4096][256] + gn partial sums
//  KB fold_all:  stats + fold groupnorm into QKV weights + w_out cast
//  KC gemm_qkv_mfma: qkv = w2b @ x (bf16 MFMA). Outputs qt[h][pos][32]
//                (Q pre-scaled LOG2E/sqrt(d)), ktb[h][pos][32],
//                v16[h][j/16][32][16]
//  KD attn_mfma: r11 structure (512 blocks x 512 thr, 64 q/block, 8 waves
//                j-split, 2x-unrolled prefetch, chunked merge). r12 change
//                (VALU diet): P pack = TRUNCATION in plain C (6 ops/4 elems,
//                fusible to v_perm) instead of ~80-op software RNE; softmax
//                denominator = ones-row MFMA over the SAME truncated p-bits
//                (self-consistent -> truncation bias cancels in p/l ratio;
//                fp32 accum on the 23%-busy MFMA pipe; r3-verified layout).
//  KE gemm_out_mfma: y = w_outb @ outTb^T + b_out (bf16 MFMA, f32 out)

typedef __attribute__((ext_vector_type(8))) short bf16x8;
typedef __attribute__((ext_vector_type(4))) short bf16x4;
typedef __attribute__((ext_vector_type(4))) float f32x4;
typedef __attribute__((ext_vector_type(4))) unsigned short u16x4;

__device__ inline unsigned short f2bf(float f) {
  __hip_bfloat16 h = __float2bfloat16(f);
  return *reinterpret_cast<unsigned short*>(&h);
}

// ---------------- KA: transpose + groupnorm partial sums ----------------
__global__ __launch_bounds__(256) void xt_gn_kernel(const float* __restrict__ x,
                                                    unsigned short* __restrict__ xTb,
                                                    float2* __restrict__ psum2) {
  __shared__ float tile[64][65];
  __shared__ float red[4][4];
  int nb = blockIdx.x * 64, cb = blockIdx.y * 64;
  int tn = threadIdx.x & 63, t4 = threadIdx.x >> 6;
  float slo = 0.f, qlo = 0.f, shi = 0.f, qhi = 0.f;
#pragma unroll
  for (int i = 0; i < 16; ++i) {
    int cc = t4 + i * 4;
    float v = x[(size_t)(cb + cc) * 4096 + nb + tn];
    tile[cc][tn] = v;
    if (i < 8) { slo += v; qlo += v * v; } else { shi += v; qhi += v * v; }
  }
#pragma unroll
  for (int off = 32; off > 0; off >>= 1) {
    slo += __shfl_down(slo, off); qlo += __shfl_down(qlo, off);
    shi += __shfl_down(shi, off); qhi += __shfl_down(qhi, off);
  }
  if ((threadIdx.x & 63) == 0) {
    red[t4][0] = slo; red[t4][1] = qlo; red[t4][2] = shi; red[t4][3] = qhi;
  }
  __syncthreads();
  if (threadIdx.x == 0) {
    float a = (red[0][0] + red[1][0]) + (red[2][0] + red[3][0]);
    float b = (red[0][1] + red[1][1]) + (red[2][1] + red[3][1]);
    psum2[(blockIdx.y * 2) * 64 + blockIdx.x] = make_float2(a, b);
  } else if (threadIdx.x == 64) {
    float a = (red[0][2] + red[1][2]) + (red[2][2] + red[3][2]);
    float b = (red[0][3] + red[1][3]) + (red[2][3] + red[3][3]);
    psum2[(blockIdx.y * 2 + 1) * 64 + blockIdx.x] = make_float2(a, b);
  }
#pragma unroll
  for (int i = 0; i < 16; ++i) {
    int nn = t4 + i * 4;
    xTb[(size_t)(nb + nn) * 256 + cb + tn] = f2bf(tile[tn][nn]);
  }
}

// ---------------- KB: stats + fold + w_out cast ----------------
__global__ __launch_bounds__(256) void fold_all_kernel(const float* __restrict__ w_qkv,
                                                       const float* __restrict__ gnw,
                                                       const float* __restrict__ gnb,
                                                       const float2* __restrict__ psum2,
                                                       const float* __restrict__ w_out,
                                                       unsigned short* __restrict__ w2b,
                                                       float* __restrict__ bias0,
                                                       unsigned short* __restrict__ w_outb) {
  int bid = blockIdx.x;
  int t = threadIdx.x;
  if (bid >= 192) {  // w_out -> bf16
    int i = ((bid - 192) * 256 + t) * 4;
    float4 v = *(const float4*)(w_out + i);
    u16x4 o;
    o[0] = f2bf(v.x); o[1] = f2bf(v.y); o[2] = f2bf(v.z); o[3] = f2bf(v.w);
    *(u16x4*)(w_outb + i) = o;
    return;
  }
  __shared__ float sm[8], sr[8];
  __shared__ float s_al[256], s_be[256];
  {
    int g = t >> 5, ii = t & 31;
    float2 p0 = psum2[g * 64 + ii];
    float2 p1 = psum2[g * 64 + 32 + ii];
    float s = p0.x + p1.x, q = p0.y + p1.y;
#pragma unroll
    for (int off = 16; off > 0; off >>= 1) {
      s += __shfl_xor(s, off);
      q += __shfl_xor(q, off);
    }
    if (ii == 0) {
      float mean = s * (1.f / 131072.f);
      float var = q * (1.f / 131072.f) - mean * mean;
      sm[g] = mean;
      sr[g] = rsqrtf(var + 1e-5f);
    }
  }
  __syncthreads();
  {
    int c = t, gg = c >> 5;
    float mean = sm[gg], rstd = sr[gg];
    float al = rstd * gnw[c];
    s_al[c] = al;
    s_be[c] = gnb[c] - mean * al;
  }
  __syncthreads();
  int w = t >> 6, lane = t & 63;
  int row = bid * 4 + w;
  float4 v = *(const float4*)(w_qkv + row * 256 + lane * 4);
  int c0 = lane * 4;
  float part = (v.x * s_be[c0] + v.y * s_be[c0 + 1]) +
               (v.z * s_be[c0 + 2] + v.w * s_be[c0 + 3]);
  u16x4 o;
  o[0] = f2bf(v.x * s_al[c0]);
  o[1] = f2bf(v.y * s_al[c0 + 1]);
  o[2] = f2bf(v.z * s_al[c0 + 2]);
  o[3] = f2bf(v.w * s_al[c0 + 3]);
  *(u16x4*)(w2b + row * 256 + c0) = o;
#pragma unroll
  for (int off = 32; off > 0; off >>= 1) part += __shfl_down(part, off);
  if (lane == 0) bias0[row] = part;
}

// ---------------- KC: qkv GEMM, bf16 MFMA ----------------
__global__ __launch_bounds__(256) void gemm_qkv_mfma(const unsigned short* __restrict__ w2b,
                                                     const unsigned short* __restrict__ xTb,
                                                     const float* __restrict__ bias0,
                                                     unsigned short* __restrict__ qt,
                                                     unsigned short* __restrict__ ktb,
                                                     unsigned short* __restrict__ v16) {
  const int nb = blockIdx.x, mb = blockIdx.y;
  const int t = threadIdx.x;
  const int w = t >> 6, lane = t & 63;
  const int c = lane & 15, g = lane >> 4;
  const int m0 = mb * 64 + w * 16;
  const int n0 = nb * 64;
  const f32x4 zero4 = {0.f, 0.f, 0.f, 0.f};

  const unsigned short* ap = w2b + (size_t)(m0 + c) * 256 + g * 8;
  bf16x8 af[8];
#pragma unroll
  for (int ks = 0; ks < 8; ++ks) af[ks] = *(const bf16x8*)(ap + ks * 32);

  f32x4 acc[4] = {zero4, zero4, zero4, zero4};
  const unsigned short* bp = xTb + (size_t)(n0 + c) * 256 + g * 8;
#pragma unroll
  for (int half = 0; half < 2; ++half) {
    bf16x8 bf[4][4];
#pragma unroll
    for (int nt = 0; nt < 4; ++nt)
#pragma unroll
      for (int k2 = 0; k2 < 4; ++k2)
        bf[nt][k2] = *(const bf16x8*)(bp + (size_t)nt * 4096 + half * 128 + k2 * 32);
#pragma unroll
    for (int k2 = 0; k2 < 4; ++k2)
#pragma unroll
      for (int nt = 0; nt < 4; ++nt)
        acc[nt] = __builtin_amdgcn_mfma_f32_16x16x32_bf16(af[half * 4 + k2], bf[nt][k2],
                                                          acc[nt], 0, 0, 0);
  }

  const int o0 = m0 + g * 4;
  const int t3 = o0 >> 8;
  const int h = (o0 >> 5) & 7;
  const int d0 = o0 & 31;
  float b4[4];
#pragma unroll
  for (int r = 0; r < 4; ++r) b4[r] = bias0[o0 + r];
  // Q pre-scale: 1/sqrt(32) * log2(e) so scores exit QK^T in log2 units
  const float qs = 0.17677669529663687f * 1.4426950408889634f;
#pragma unroll
  for (int nt = 0; nt < 4; ++nt) {
    int n = n0 + nt * 16 + c;
    if (t3 == 0) {
      u16x4 v;
#pragma unroll
      for (int r = 0; r < 4; ++r) v[r] = f2bf((acc[nt][r] + b4[r]) * qs);
      *(u16x4*)(qt + (size_t)(h * 4096 + n) * 32 + d0) = v;
    } else if (t3 == 1) {
      u16x4 v;
#pragma unroll
      for (int r = 0; r < 4; ++r) v[r] = f2bf(acc[nt][r] + b4[r]);
      *(u16x4*)(ktb + (size_t)(h * 4096 + n) * 32 + d0) = v;
    } else {
#pragma unroll
      for (int r = 0; r < 4; ++r)
        v16[(size_t)((h * 256 + (n >> 4)) * 32 + d0 + r) * 16 + (n & 15)] =
            f2bf(acc[nt][r] + b4[r]);
    }
  }
}

// ---------------- KD: MFMA flash attention, no online max ----------------
// One (jt) compute step over a 64j x 64q tile set.
// P pack: truncation (top 16 bits). Denominator: ones-row MFMA over the
// SAME truncated bits (self-consistent; bias cancels in p/l; fp32 accum).
__device__ __forceinline__ void attn_step(const bf16x8* kf, const bf16x4 vf[2][4],
                                          const bf16x8* qf, f32x4 (*oacc)[2],
                                          f32x4* lones) {
  const f32x4 zero4 = {0.f, 0.f, 0.f, 0.f};
  const short one_bf = (short)0x3F80;
  const bf16x4 onesv = {one_bf, one_bf, one_bf, one_bf};
#pragma unroll
  for (int it = 0; it < 4; ++it) {
    f32x4 st[4];
    __builtin_amdgcn_s_setprio(1);
#pragma unroll
    for (int js = 0; js < 4; ++js)
      st[js] = __builtin_amdgcn_mfma_f32_16x16x32_bf16(kf[js], qf[it], zero4, 0, 0, 0);
    __builtin_amdgcn_s_setprio(0);
    bf16x4 pb[4];
#pragma unroll
    for (int js = 0; js < 4; ++js) {
      // scores already in log2 units (Q pre-scaled by LOG2E/sqrt(d))
      unsigned u0 = __float_as_uint(__builtin_amdgcn_exp2f(st[js][0]));
      unsigned u1 = __float_as_uint(__builtin_amdgcn_exp2f(st[js][1]));
      unsigned u2 = __float_as_uint(__builtin_amdgcn_exp2f(st[js][2]));
      unsigned u3 = __float_as_uint(__builtin_amdgcn_exp2f(st[js][3]));
      union { unsigned u[2]; bf16x4 v; } pu;
      pu.u[0] = (u0 >> 16) | (u1 & 0xFFFF0000u);  // elem0=bf16(p0), elem1=bf16(p1)
      pu.u[1] = (u2 >> 16) | (u3 & 0xFFFF0000u);
      pb[js] = pu.v;
    }
    __builtin_amdgcn_s_setprio(1);
#pragma unroll
    for (int js = 0; js < 4; ++js) {
      oacc[it][0] = __builtin_amdgcn_mfma_f32_16x16x16bf16_1k(vf[0][js], pb[js], oacc[it][0], 0, 0, 0);
      oacc[it][1] = __builtin_amdgcn_mfma_f32_16x16x16bf16_1k(vf[1][js], pb[js], oacc[it][1], 0, 0, 0);
      lones[it] = __builtin_amdgcn_mfma_f32_16x16x16bf16_1k(onesv, pb[js], lones[it], 0, 0, 0);
    }
    __builtin_amdgcn_s_setprio(0);
  }
}

// 512 blocks x 512 threads: h = b&7 (XCD affinity), i0 = (b>>3)*64.
// 8 waves split j (512 each). 2x-unrolled jt pipeline, two K+V register sets.
__global__ __launch_bounds__(512, 1) void attn_mfma_kernel(const unsigned short* __restrict__ qt,
                                                           const unsigned short* __restrict__ ktb,
                                                           const unsigned short* __restrict__ v16,
                                                           unsigned short* __restrict__ outTb) {
  const int b = blockIdx.x;
  const int h = b & 7;
  const int i0 = (b >> 3) * 64;
  const int t = threadIdx.x;
  const int w = t >> 6;
  const int lane = t & 63;
  const int c = lane & 15;
  const int g = lane >> 4;
  const f32x4 zero4 = {0.f, 0.f, 0.f, 0.f};

  const unsigned short* qb = qt + (size_t)h * 131072 + (size_t)(i0 + c) * 32 + g * 8;
  bf16x8 qf[4];
#pragma unroll
  for (int it = 0; it < 4; ++it) qf[it] = *(const bf16x8*)(qb + it * 512);

  const unsigned short* kp = ktb + (size_t)h * 131072 + (size_t)(w * 512 + c) * 32 + g * 8;
  const unsigned short* vp = v16 + (size_t)((h * 256 + w * 32) * 32 + c) * 16 + g * 4;

  f32x4 lones[4] = {zero4, zero4, zero4, zero4};
  f32x4 oacc[4][2];
#pragma unroll
  for (int it = 0; it < 4; ++it) {
    oacc[it][0] = zero4;
    oacc[it][1] = zero4;
  }

#define KLOAD(dst, tt)                                         \
  _Pragma("unroll") for (int js = 0; js < 4; ++js)             \
      dst[js] = *(const bf16x8*)(kp + (tt) * 2048 + js * 512);
#define VLOAD(dst, tt)                                                        \
  _Pragma("unroll") for (int dh = 0; dh < 2; ++dh)                            \
      _Pragma("unroll") for (int js = 0; js < 4; ++js)                        \
          dst[dh][js] = *(const bf16x4*)(vp + ((tt) * 4 + js) * 512 + dh * 256);

  bf16x8 kfA[4], kfB[4];
  bf16x4 vfA[2][4], vfB[2][4];
  KLOAD(kfA, 0);
  VLOAD(vfA, 0);

#pragma unroll 1
  for (int jt2 = 0; jt2 < 4; ++jt2) {
    const int base = jt2 * 2;
    KLOAD(kfB, base + 1);
    VLOAD(vfB, base + 1);
    attn_step(kfA, vfA, qf, oacc, lones);
    if (jt2 < 3) {
      KLOAD(kfA, base + 2);
      VLOAD(vfA, base + 2);
    }
    attn_step(kfB, vfB, qf, oacc, lones);
  }
#undef KLOAD
#undef VLOAD

  // ---- merge 8 waves' partials, chunked per i-tile (LDS ~19.5KB) ----
  // ones-MFMA puts the full column sum Sum_j p~[j][c] in every acc element,
  // so lones[it][0] is the per-query denominator directly (no shfl needed).
  __shared__ float lds_o[8][2][4][4][17];  // [w][dh][g][r][c] (one i-tile)
  __shared__ float lds_l[8][4][16];
#pragma unroll
  for (int it = 0; it < 4; ++it) {
    if (g == 0) lds_l[w][it][c] = lones[it][0];
  }
#pragma unroll 1
  for (int itc = 0; itc < 4; ++itc) {
#pragma unroll
    for (int dh = 0; dh < 2; ++dh)
#pragma unroll
      for (int r = 0; r < 4; ++r)
        lds_o[w][dh][g][r][c] = oacc[itc][dh][r];
    __syncthreads();
    if (w < 2) {
      const int dh = w;
      float L = ((lds_l[0][itc][c] + lds_l[1][itc][c]) + (lds_l[2][itc][c] + lds_l[3][itc][c])) +
                ((lds_l[4][itc][c] + lds_l[5][itc][c]) + (lds_l[6][itc][c] + lds_l[7][itc][c]));
      float inv = 1.f / L;
      u16x4 o;
#pragma unroll
      for (int r = 0; r < 4; ++r) {
        float v = ((lds_o[0][dh][g][r][c] + lds_o[1][dh][g][r][c]) +
                   (lds_o[2][dh][g][r][c] + lds_o[3][dh][g][r][c])) +
                  ((lds_o[4][dh][g][r][c] + lds_o[5][dh][g][r][c]) +
                   (lds_o[6][dh][g][r][c] + lds_o[7][dh][g][r][c]));
        o[r] = f2bf(v * inv);
      }
      *(u16x4*)(outTb + (size_t)(i0 + itc * 16 + c) * 256 + h * 32 + dh * 16 + g * 4) = o;
    }
    __syncthreads();
  }
}

// ---------------- KE: y = w_outb @ outTb^T + b_out (bf16 MFMA) ----------------
__global__ __launch_bounds__(256) void gemm_out_mfma(const unsigned short* __restrict__ w_outb,
                                                     const unsigned short* __restrict__ outTb,
                                                     const float* __restrict__ bias,
                                                     float* __restrict__ y) {
  const int nb = blockIdx.x, mb = blockIdx.y;
  const int t = threadIdx.x;
  const int w = t >> 6, lane = t & 63;
  const int c = lane & 15, g = lane >> 4;
  const int m0 = mb * 64 + w * 16;
  const int n0 = nb * 64;
  const f32x4 zero4 = {0.f, 0.f, 0.f, 0.f};

  const unsigned short* ap = w_outb + (size_t)(m0 + c) * 256 + g * 8;
  bf16x8 af[8];
#pragma unroll
  for (int ks = 0; ks < 8; ++ks) af[ks] = *(const bf16x8*)(ap + ks * 32);

  f32x4 acc[4] = {zero4, zero4, zero4, zero4};
  const unsigned short* bp = outTb + (size_t)(n0 + c) * 256 + g * 8;
#pragma unroll
  for (int half = 0; half < 2; ++half) {
    bf16x8 bf[4][4];
#pragma unroll
    for (int nt = 0; nt < 4; ++nt)
#pragma unroll
      for (int k2 = 0; k2 < 4; ++k2)
        bf[nt][k2] = *(const bf16x8*)(bp + (size_t)nt * 4096 + half * 128 + k2 * 32);
#pragma unroll
    for (int k2 = 0; k2 < 4; ++k2)
#pragma unroll
      for (int nt = 0; nt < 4; ++nt)
        acc[nt] = __builtin_amdgcn_mfma_f32_16x16x32_bf16(af[half * 4 + k2], bf[nt][k2],
                                                          acc[nt], 0, 0, 0);
  }

  const int o0 = m0 + g * 4;
  float b4[4];
#pragma unroll
  for (int r = 0; r < 4; ++r) b4[r] = bias[o0 + r];
#pragma unroll
  for (int nt = 0; nt < 4; ++nt) {
    int n = n0 + nt * 16 + c;
#pragma unroll
    for (int r = 0; r < 4; ++r)
      y[(size_t)(o0 + r) * 4096 + n] = acc[nt][r] + b4[r];
  }
}

extern "C" void kernel_launch(void* const* d_in, const int* in_sizes, int n_in,
                              void* d_out, int out_size, void* d_ws, size_t ws_size,
                              hipStream_t stream) {
  const float* x = (const float*)d_in[0];
  const float* gnw = (const float*)d_in[1];
  const float* gnb = (const float*)d_in[2];
  const float* w_qkv = (const float*)d_in[3];
  const float* w_out = (const float*)d_in[4];
  const float* b_out = (const float*)d_in[5];
  float* ws = (float*)d_ws;

  float2* psum2 = (float2*)ws;                         // 512 float2
  float* bias0 = ws + 1088;                            // 768
  unsigned short* w2b = (unsigned short*)(ws + 2048);  // 768*256 u16
  unsigned short* w_outb = w2b + 196608;               // 256*256 u16
  unsigned short* xTb = w_outb + 65536;                // 4096*256 u16
  unsigned short* qt = xTb + 1048576;                  // 8*4096*32 u16
  unsigned short* ktb = qt + 1048576;
  unsigned short* v16 = ktb + 1048576;                 // tiled V
  unsigned short* outTb = v16 + 1048576;               // 4096*256 u16
  float* y = (float*)d_out;

  hipLaunchKernelGGL(xt_gn_kernel, dim3(64, 4), dim3(256), 0, stream, x, xTb, psum2);
  hipLaunchKernelGGL(fold_all_kernel, dim3(256), dim3(256), 0, stream, w_qkv, gnw, gnb,
                     psum2, w_out, w2b, bias0, w_outb);
  hipLaunchKernelGGL(gemm_qkv_mfma, dim3(64, 12), dim3(256), 0, stream, w2b, xTb, bias0, qt, ktb, v16);
  hipLaunchKernelGGL(attn_mfma_kernel, dim3(512), dim3(512), 0, stream, qt, ktb, v16, outTb);
  hipLaunchKernelGGL(gemm_out_mfma, dim3(64, 4), dim3(256), 0, stream, w_outb, outTb, b_out, y);
}